// Round 7
// baseline (217.067 us; speedup 1.0000x reference)
//
#include <hip/hip_runtime.h>

#define NB    2048
#define AMAX  64
#define EDIM  128
#define TOTAL 66560          // = 520 * 128
#define DHEAD 16
#define KVSTR 20
#define XSTR  129
#define LSTR  136            // LDS row stride in fp16 (128 + 8 pad)

typedef _Float16 f16x8 __attribute__((ext_vector_type(8)));
typedef _Float16 f16x4 __attribute__((ext_vector_type(4)));
typedef float    f32x4 __attribute__((ext_vector_type(4)));

// ---------------- offsets: exclusive prefix sum ----------------
__global__ __launch_bounds__(256) void scan_kernel(const int* __restrict__ ag,
                                                   int* __restrict__ offs) {
    __shared__ int part[256];
    const int t = threadIdx.x;
    int loc[8];
    int s = 0;
#pragma unroll
    for (int i = 0; i < 8; ++i) { loc[i] = s; s += ag[t * 8 + i]; }
    part[t] = s;
    __syncthreads();
    for (int d = 1; d < 256; d <<= 1) {
        int v = (t >= d) ? part[t - d] : 0;
        __syncthreads();
        part[t] += v;
        __syncthreads();
    }
    const int base = (t == 0) ? 0 : part[t - 1];
#pragma unroll
    for (int i = 0; i < 8; ++i) offs[t * 8 + i] = base + loc[i];
}

// ---------------- QKV GEMM: qkv_h[M x 384] = x_f32[M x 128] @ win^T + bin ----------------
__global__ __launch_bounds__(256, 2) void gemm_qkv_kernel(
    const float* __restrict__ Ain,   // f32 [M][128]
    const float* __restrict__ Bin,   // f32 [384][128]
    const float* __restrict__ bias,  // f32 [384]
    _Float16*    __restrict__ Cout)  // f16 [M][384]
{
    __shared__ __align__(16) _Float16 As[128 * LSTR];
    __shared__ __align__(16) _Float16 Bs[128 * LSTR];
    const int tid = threadIdx.x;
    const int rowbase = blockIdx.y * 128;
    const int colbase = blockIdx.x * 128;

    {
        const float* A = Ain + (size_t)rowbase * EDIM;
        const float* B = Bin + (size_t)colbase * EDIM;
#pragma unroll
        for (int it = 0; it < 8; ++it) {
            const int u = it * 256 + tid;            // 2048 units of 8 halfs
            const int r = u >> 4, c8 = u & 15;
            const float4 a0 = *(const float4*)(A + r * EDIM + c8 * 8);
            const float4 a1 = *(const float4*)(A + r * EDIM + c8 * 8 + 4);
            const float4 b0 = *(const float4*)(B + r * EDIM + c8 * 8);
            const float4 b1 = *(const float4*)(B + r * EDIM + c8 * 8 + 4);
            f16x8 ha, hb;
            ha[0]=(_Float16)a0.x; ha[1]=(_Float16)a0.y; ha[2]=(_Float16)a0.z; ha[3]=(_Float16)a0.w;
            ha[4]=(_Float16)a1.x; ha[5]=(_Float16)a1.y; ha[6]=(_Float16)a1.z; ha[7]=(_Float16)a1.w;
            hb[0]=(_Float16)b0.x; hb[1]=(_Float16)b0.y; hb[2]=(_Float16)b0.z; hb[3]=(_Float16)b0.w;
            hb[4]=(_Float16)b1.x; hb[5]=(_Float16)b1.y; hb[6]=(_Float16)b1.z; hb[7]=(_Float16)b1.w;
            *(f16x8*)(As + r * LSTR + c8 * 8) = ha;
            *(f16x8*)(Bs + r * LSTR + c8 * 8) = hb;
        }
    }
    __syncthreads();

    const int lane = tid & 63;
    const int wid  = __builtin_amdgcn_readfirstlane(tid >> 6);
    const int l15  = lane & 15;
    const int quad = lane >> 4;

    f32x4 acc[2][8];
#pragma unroll
    for (int r = 0; r < 2; ++r)
#pragma unroll
        for (int c = 0; c < 8; ++c) acc[r][c] = (f32x4){0.f, 0.f, 0.f, 0.f};

#pragma unroll
    for (int ks = 0; ks < 4; ++ks) {
        f16x8 cfrag[8], rfrag[2];
#pragma unroll
        for (int c = 0; c < 8; ++c)
            cfrag[c] = *(const f16x8*)(Bs + (c * 16 + l15) * LSTR + ks * 32 + quad * 8);
#pragma unroll
        for (int r = 0; r < 2; ++r)
            rfrag[r] = *(const f16x8*)(As + (wid * 32 + r * 16 + l15) * LSTR + ks * 32 + quad * 8);
#pragma unroll
        for (int r = 0; r < 2; ++r)
#pragma unroll
            for (int c = 0; c < 8; ++c)
                acc[r][c] = __builtin_amdgcn_mfma_f32_16x16x32_f16(cfrag[c], rfrag[r], acc[r][c], 0, 0, 0);
    }

#pragma unroll
    for (int r = 0; r < 2; ++r) {
        const size_t row = rowbase + wid * 32 + r * 16 + l15;
#pragma unroll
        for (int c = 0; c < 8; ++c) {
            const int col = colbase + c * 16 + quad * 4;
            const float4 bv = *(const float4*)(bias + col);
            const f32x4 a = acc[r][c];
            f16x4 h;
            h[0] = (_Float16)(a[0] + bv.x); h[1] = (_Float16)(a[1] + bv.y);
            h[2] = (_Float16)(a[2] + bv.z); h[3] = (_Float16)(a[3] + bv.w);
            *(f16x4*)(Cout + row * 384 + col) = h;
        }
    }
}

// ---------------- out-proj GEMM: out_f32[M x 128] = ctx_h[M x 128] @ wout^T + bout ----------------
__global__ __launch_bounds__(256, 2) void gemm_out_kernel(
    const _Float16* __restrict__ Ain,   // f16 [M][128]
    const float*    __restrict__ Bin,   // f32 [128][128]
    const float*    __restrict__ bias,  // f32 [128]
    float*          __restrict__ Cout)  // f32 [M][128]
{
    __shared__ __align__(16) _Float16 As[128 * LSTR];
    __shared__ __align__(16) _Float16 Bs[128 * LSTR];
    const int tid = threadIdx.x;
    const int rowbase = blockIdx.y * 128;

    {
        const _Float16* A = Ain + (size_t)rowbase * EDIM;
#pragma unroll
        for (int it = 0; it < 8; ++it) {
            const int u = it * 256 + tid;
            const int r = u >> 4, c8 = u & 15;
            *(f16x8*)(As + r * LSTR + c8 * 8) = *(const f16x8*)(A + r * EDIM + c8 * 8);
            const float4 b0 = *(const float4*)(Bin + r * EDIM + c8 * 8);
            const float4 b1 = *(const float4*)(Bin + r * EDIM + c8 * 8 + 4);
            f16x8 hb;
            hb[0]=(_Float16)b0.x; hb[1]=(_Float16)b0.y; hb[2]=(_Float16)b0.z; hb[3]=(_Float16)b0.w;
            hb[4]=(_Float16)b1.x; hb[5]=(_Float16)b1.y; hb[6]=(_Float16)b1.z; hb[7]=(_Float16)b1.w;
            *(f16x8*)(Bs + r * LSTR + c8 * 8) = hb;
        }
    }
    __syncthreads();

    const int lane = tid & 63;
    const int wid  = __builtin_amdgcn_readfirstlane(tid >> 6);
    const int l15  = lane & 15;
    const int quad = lane >> 4;

    f32x4 acc[2][8];
#pragma unroll
    for (int r = 0; r < 2; ++r)
#pragma unroll
        for (int c = 0; c < 8; ++c) acc[r][c] = (f32x4){0.f, 0.f, 0.f, 0.f};

#pragma unroll
    for (int ks = 0; ks < 4; ++ks) {
        f16x8 cfrag[8], rfrag[2];
#pragma unroll
        for (int c = 0; c < 8; ++c)
            cfrag[c] = *(const f16x8*)(Bs + (c * 16 + l15) * LSTR + ks * 32 + quad * 8);
#pragma unroll
        for (int r = 0; r < 2; ++r)
            rfrag[r] = *(const f16x8*)(As + (wid * 32 + r * 16 + l15) * LSTR + ks * 32 + quad * 8);
#pragma unroll
        for (int r = 0; r < 2; ++r)
#pragma unroll
            for (int c = 0; c < 8; ++c)
                acc[r][c] = __builtin_amdgcn_mfma_f32_16x16x32_f16(cfrag[c], rfrag[r], acc[r][c], 0, 0, 0);
    }

#pragma unroll
    for (int r = 0; r < 2; ++r) {
        const size_t row = rowbase + wid * 32 + r * 16 + l15;
#pragma unroll
        for (int c = 0; c < 8; ++c) {
            const int col = c * 16 + quad * 4;
            const float4 bv = *(const float4*)(bias + col);
            const f32x4 a = acc[r][c];
            *(float4*)(Cout + row * 128 + col) =
                make_float4(a[0] + bv.x, a[1] + bv.y, a[2] + bv.z, a[3] + bv.w);
        }
    }
}

// ---------------- per-sample-PAIR flash attention over fp16 QKV ----------------
// block blk handles samples blk and 2047-blk: n0+n1 ~ 59 nearly constant ->
// balanced blocks; grid 1024 = 4 blocks/CU in one dispatch wave.
// Inner body identical to the round-5 proven kernel (fp32 K/V in LDS, fmaf dots).
__global__ __launch_bounds__(256, 4) void attn2h_kernel(
    const _Float16* __restrict__ qkv,   // [TOTAL][384] fp16
    const int*      __restrict__ ag,
    const int*      __restrict__ offs,
    _Float16*       __restrict__ ctx)   // [TOTAL][128] fp16
{
    __shared__ __align__(16) float kvs[8][AMAX * KVSTR];   // 40 KB; 4 blocks/CU = 160 KiB
    const int tid  = threadIdx.x;
    const int lane = tid & 63;
    const int wid  = __builtin_amdgcn_readfirstlane(tid >> 6);
    float* kw = kvs[wid * 2 + 0];
    float* vw = kvs[wid * 2 + 1];

#pragma unroll
    for (int sp = 0; sp < 2; ++sp) {
        const int b   = sp ? (NB - 1 - blockIdx.x) : blockIdx.x;
        const int n   = ag[b];
        const int off = offs[b];
        const bool valid = lane < n;
        const _Float16* rowp = qkv + (size_t)(off + lane) * 384;

#pragma unroll
        for (int m = 0; m < 2; ++m) {
            const int h = wid * 2 + m;
            float qa[DHEAD], ka[DHEAD], va[DHEAD];
            if (valid) {
                const f16x8 q0 = *(const f16x8*)(rowp + h * 16);
                const f16x8 q1 = *(const f16x8*)(rowp + h * 16 + 8);
                const f16x8 k0 = *(const f16x8*)(rowp + 128 + h * 16);
                const f16x8 k1 = *(const f16x8*)(rowp + 128 + h * 16 + 8);
                const f16x8 v0 = *(const f16x8*)(rowp + 256 + h * 16);
                const f16x8 v1 = *(const f16x8*)(rowp + 256 + h * 16 + 8);
#pragma unroll
                for (int d = 0; d < 8; ++d) {
                    qa[d] = (float)q0[d]; qa[d + 8] = (float)q1[d];
                    ka[d] = (float)k0[d]; ka[d + 8] = (float)k1[d];
                    va[d] = (float)v0[d]; va[d + 8] = (float)v1[d];
                }
            } else {
#pragma unroll
                for (int d = 0; d < DHEAD; ++d) { qa[d] = 0.f; ka[d] = 0.f; va[d] = 0.f; }
            }
#pragma unroll
            for (int d = 0; d < DHEAD; ++d) qa[d] *= 0.25f;   // 1/sqrt(16)
            // wave-private LDS stash, no barrier needed
#pragma unroll
            for (int d4 = 0; d4 < 4; ++d4) {
                *(float4*)(kw + lane * KVSTR + d4 * 4) = make_float4(ka[d4*4], ka[d4*4+1], ka[d4*4+2], ka[d4*4+3]);
                *(float4*)(vw + lane * KVSTR + d4 * 4) = make_float4(va[d4*4], va[d4*4+1], va[d4*4+2], va[d4*4+3]);
            }

            float mrun = -1e30f, lrun = 0.f;
            float cacc[DHEAD];
#pragma unroll
            for (int d = 0; d < DHEAD; ++d) cacc[d] = 0.f;
            const int nch = (n + 15) >> 4;
            for (int ch = 0; ch < nch; ++ch) {
                const int jb = ch << 4;
                float s[16], p[16];
#pragma unroll
                for (int jj = 0; jj < 16; ++jj) {
                    const float4* kr = (const float4*)(kw + (jb + jj) * KVSTR);
                    const float4 k0 = kr[0], k1 = kr[1], k2 = kr[2], k3 = kr[3];
                    const float kk[16] = {k0.x,k0.y,k0.z,k0.w, k1.x,k1.y,k1.z,k1.w,
                                          k2.x,k2.y,k2.z,k2.w, k3.x,k3.y,k3.z,k3.w};
                    float a = 0.f;
#pragma unroll
                    for (int d = 0; d < DHEAD; ++d) a = fmaf(qa[d], kk[d], a);
                    s[jj] = (jb + jj < n) ? a : -1e30f;
                }
                float mc = s[0];
#pragma unroll
                for (int jj = 1; jj < 16; ++jj) mc = fmaxf(mc, s[jj]);
                const float mnew  = fmaxf(mrun, mc);
                const float alpha = __expf(mrun - mnew);
                float psum = 0.f;
#pragma unroll
                for (int jj = 0; jj < 16; ++jj) { p[jj] = __expf(s[jj] - mnew); psum += p[jj]; }
                lrun = fmaf(lrun, alpha, psum);
#pragma unroll
                for (int d = 0; d < DHEAD; ++d) cacc[d] *= alpha;
#pragma unroll
                for (int jj = 0; jj < 16; ++jj) {
                    const float4* vr = (const float4*)(vw + (jb + jj) * KVSTR);
                    const float4 v0 = vr[0], v1 = vr[1], v2 = vr[2], v3 = vr[3];
                    const float vv[16] = {v0.x,v0.y,v0.z,v0.w, v1.x,v1.y,v1.z,v1.w,
                                          v2.x,v2.y,v2.z,v2.w, v3.x,v3.y,v3.z,v3.w};
                    const float pj = p[jj];
#pragma unroll
                    for (int d = 0; d < DHEAD; ++d) cacc[d] = fmaf(pj, vv[d], cacc[d]);
                }
                mrun = mnew;
            }
            if (valid) {
                const float inv = 1.0f / lrun;
                f16x8 o0, o1;
#pragma unroll
                for (int d = 0; d < 8; ++d) {
                    o0[d] = (_Float16)(cacc[d] * inv);
                    o1[d] = (_Float16)(cacc[d + 8] * inv);
                }
                _Float16* crow = ctx + (size_t)(off + lane) * 128 + h * 16;
                *(f16x8*)(crow)     = o0;
                *(f16x8*)(crow + 8) = o1;
            }
        }
    }
}

// ================= fallback: fused fp32 kernel (used if ws too small) =================
__global__ __launch_bounds__(256, 2) void attn_fused_kernel(
    const float* __restrict__ x, const float* __restrict__ win,
    const float* __restrict__ bin, const float* __restrict__ wout,
    const float* __restrict__ bout, const int* __restrict__ ag,
    const int* __restrict__ offs, float* __restrict__ out)
{
    __shared__ __align__(16) float xs[AMAX * XSTR];
    __shared__ __align__(16) float kvs[8][AMAX * KVSTR];
    const int b = blockIdx.x, n = ag[b], off = offs[b];
    const int tid = threadIdx.x, lane = tid & 63;
    const int wid = __builtin_amdgcn_readfirstlane(tid >> 6);
#pragma unroll
    for (int it = 0; it < 8; ++it) {
        const int f4 = it * 256 + tid;
        const int r = f4 >> 5, c = (f4 & 31) << 2;
        float4 v = make_float4(0.f, 0.f, 0.f, 0.f);
        if (r < n) v = *(const float4*)(x + (size_t)(off + r) * EDIM + c);
        float* d = xs + r * XSTR + c;
        d[0]=v.x; d[1]=v.y; d[2]=v.z; d[3]=v.w;
    }
    __syncthreads();
    float* kw = kvs[wid*2+0]; float* vw = kvs[wid*2+1];
    const float* xrow = xs + lane * XSTR;
    float ctxk[2][DHEAD];
#pragma unroll
    for (int m = 0; m < 2; ++m) {
        const int h = wid * 2 + m;
        float qa[DHEAD], ka[DHEAD], va[DHEAD];
#pragma unroll
        for (int d = 0; d < DHEAD; ++d) { qa[d]=0.f; ka[d]=0.f; va[d]=0.f; }
        const float* wq = win + (size_t)(h*DHEAD)*EDIM;
        const float* wk = win + (size_t)(EDIM + h*DHEAD)*EDIM;
        const float* wv = win + (size_t)(2*EDIM + h*DHEAD)*EDIM;
        for (int k = 0; k < EDIM; ++k) {
            const float xv = xrow[k];
#pragma unroll
            for (int d = 0; d < DHEAD; ++d) {
                qa[d] = fmaf(xv, wq[d*EDIM+k], qa[d]);
                ka[d] = fmaf(xv, wk[d*EDIM+k], ka[d]);
                va[d] = fmaf(xv, wv[d*EDIM+k], va[d]);
            }
        }
#pragma unroll
        for (int d = 0; d < DHEAD; ++d) {
            qa[d] = (qa[d] + bin[h*DHEAD+d]) * 0.25f;
            ka[d] += bin[EDIM + h*DHEAD + d];
            va[d] += bin[2*EDIM + h*DHEAD + d];
        }
#pragma unroll
        for (int d = 0; d < DHEAD; ++d) { kw[lane*KVSTR+d] = ka[d]; vw[lane*KVSTR+d] = va[d]; }
        float mrun = -1e30f, lrun = 0.f, cacc[DHEAD];
#pragma unroll
        for (int d = 0; d < DHEAD; ++d) cacc[d] = 0.f;
        const int nch = (n + 15) >> 4;
        for (int ch = 0; ch < nch; ++ch) {
            const int jb = ch << 4;
            float s[16], p[16];
#pragma unroll
            for (int jj = 0; jj < 16; ++jj) {
                const float4* kr = (const float4*)(kw + (jb + jj) * KVSTR);
                const float4 k0=kr[0],k1=kr[1],k2=kr[2],k3=kr[3];
                const float kk[16] = {k0.x,k0.y,k0.z,k0.w,k1.x,k1.y,k1.z,k1.w,
                                      k2.x,k2.y,k2.z,k2.w,k3.x,k3.y,k3.z,k3.w};
                float a = 0.f;
#pragma unroll
                for (int d = 0; d < DHEAD; ++d) a = fmaf(qa[d], kk[d], a);
                s[jj] = (jb + jj < n) ? a : -1e30f;
            }
            float mc = s[0];
#pragma unroll
            for (int jj = 1; jj < 16; ++jj) mc = fmaxf(mc, s[jj]);
            const float mnew = fmaxf(mrun, mc);
            const float alpha = __expf(mrun - mnew);
            float psum = 0.f;
#pragma unroll
            for (int jj = 0; jj < 16; ++jj) { p[jj] = __expf(s[jj]-mnew); psum += p[jj]; }
            lrun = fmaf(lrun, alpha, psum);
#pragma unroll
            for (int d = 0; d < DHEAD; ++d) cacc[d] *= alpha;
#pragma unroll
            for (int jj = 0; jj < 16; ++jj) {
                const float4* vr = (const float4*)(vw + (jb + jj) * KVSTR);
                const float4 v0=vr[0],v1=vr[1],v2=vr[2],v3=vr[3];
                const float vv[16] = {v0.x,v0.y,v0.z,v0.w,v1.x,v1.y,v1.z,v1.w,
                                      v2.x,v2.y,v2.z,v2.w,v3.x,v3.y,v3.z,v3.w};
                const float pj = p[jj];
#pragma unroll
                for (int d = 0; d < DHEAD; ++d) cacc[d] = fmaf(pj, vv[d], cacc[d]);
            }
            mrun = mnew;
        }
        const float inv = 1.0f / lrun;
#pragma unroll
        for (int d = 0; d < DHEAD; ++d) ctxk[m][d] = cacc[d] * inv;
    }
    __syncthreads();
#pragma unroll
    for (int m = 0; m < 2; ++m) {
        const int h = wid * 2 + m;
#pragma unroll
        for (int d = 0; d < DHEAD; ++d) xs[lane*XSTR + h*DHEAD + d] = ctxk[m][d];
    }
    __syncthreads();
    const int c0 = wid * 32;
#pragma unroll
    for (int ct = 0; ct < 4; ++ct) {
        const int cc = c0 + ct * 8;
        float a8[8];
#pragma unroll
        for (int j = 0; j < 8; ++j) a8[j] = 0.f;
#pragma unroll 4
        for (int e = 0; e < EDIM; ++e) {
            const float cv = xrow[e];
#pragma unroll
            for (int j = 0; j < 8; ++j) a8[j] = fmaf(cv, wout[(size_t)(cc+j)*EDIM+e], a8[j]);
        }
        if (lane < n) {
            float* orow = out + (size_t)(off + lane) * EDIM + cc;
#pragma unroll
            for (int j = 0; j < 8; ++j) orow[j] = a8[j] + bout[cc+j];
        }
    }
}

extern "C" void kernel_launch(void* const* d_in, const int* in_sizes, int n_in,
                              void* d_out, int out_size, void* d_ws, size_t ws_size,
                              hipStream_t stream) {
    const float* x   = (const float*)d_in[0];
    const float* win = (const float*)d_in[1];
    const float* bin = (const float*)d_in[2];
    const float* wo  = (const float*)d_in[3];
    const float* bo  = (const float*)d_in[4];
    const int*   ag  = (const int*)d_in[5];
    float* out = (float*)d_out;

    const size_t need = (size_t)TOTAL * 512 * sizeof(_Float16) + NB * sizeof(int);
    if (ws_size >= need) {
        _Float16* qkvh = (_Float16*)d_ws;                       // [TOTAL][384]
        _Float16* ctxh = qkvh + (size_t)TOTAL * 384;            // [TOTAL][128]
        int* offs = (int*)(qkvh + (size_t)TOTAL * 512);
        scan_kernel<<<1, 256, 0, stream>>>(ag, offs);
        gemm_qkv_kernel<<<dim3(3, TOTAL / 128), 256, 0, stream>>>(x, win, bin, qkvh);
        attn2h_kernel<<<NB / 2, 256, 0, stream>>>(qkvh, ag, offs, ctxh);
        gemm_out_kernel<<<dim3(1, TOTAL / 128), 256, 0, stream>>>(ctxh, wo, bo, out);
    } else {
        int* offs = (int*)d_ws;
        scan_kernel<<<1, 256, 0, stream>>>(ag, offs);
        attn_fused_kernel<<<NB, 256, 0, stream>>>(x, win, bin, wo, bo, ag, offs, out);
    }
}

// Round 8
// 195.051 us; speedup vs baseline: 1.1129x; 1.1129x over previous
//
#include <hip/hip_runtime.h>

#define NB    2048
#define AMAX  64
#define EDIM  128
#define TOTAL 66560          // = 520 * 128
#define DHEAD 16
#define KVSTR 20
#define XSTR  129
#define LSTR  136            // LDS row stride in fp16 (128 + 8 pad)

typedef _Float16 f16x8 __attribute__((ext_vector_type(8)));
typedef _Float16 f16x4 __attribute__((ext_vector_type(4)));
typedef float    f32x4 __attribute__((ext_vector_type(4)));

// ---------------- offsets (exclusive prefix sum) + wout fp32->fp16 convert ----------------
__global__ __launch_bounds__(256) void scan_kernel(const int* __restrict__ ag,
                                                   int* __restrict__ offs,
                                                   const float* __restrict__ wout,
                                                   _Float16* __restrict__ woh) {
    __shared__ int part[256];
    const int t = threadIdx.x;
    int loc[8];
    int s = 0;
#pragma unroll
    for (int i = 0; i < 8; ++i) { loc[i] = s; s += ag[t * 8 + i]; }
    part[t] = s;
    __syncthreads();
    for (int d = 1; d < 256; d <<= 1) {
        int v = (t >= d) ? part[t - d] : 0;
        __syncthreads();
        part[t] += v;
        __syncthreads();
    }
    const int base = (t == 0) ? 0 : part[t - 1];
#pragma unroll
    for (int i = 0; i < 8; ++i) offs[t * 8 + i] = base + loc[i];
    if (woh != nullptr) {
#pragma unroll
        for (int i = 0; i < 64; ++i)
            woh[t * 64 + i] = (_Float16)wout[t * 64 + i];
    }
}

// ---------------- QKV GEMM: qkv_h[M x 384] = x_f32[M x 128] @ win^T + bin ----------------
__global__ __launch_bounds__(256, 2) void gemm_qkv_kernel(
    const float* __restrict__ Ain,   // f32 [M][128]
    const float* __restrict__ Bin,   // f32 [384][128]
    const float* __restrict__ bias,  // f32 [384]
    _Float16*    __restrict__ Cout)  // f16 [M][384]
{
    __shared__ __align__(16) _Float16 As[128 * LSTR];
    __shared__ __align__(16) _Float16 Bs[128 * LSTR];
    const int tid = threadIdx.x;
    const int rowbase = blockIdx.y * 128;
    const int colbase = blockIdx.x * 128;

    {
        const float* A = Ain + (size_t)rowbase * EDIM;
        const float* B = Bin + (size_t)colbase * EDIM;
#pragma unroll
        for (int it = 0; it < 8; ++it) {
            const int u = it * 256 + tid;            // 2048 units of 8 halfs
            const int r = u >> 4, c8 = u & 15;
            const float4 a0 = *(const float4*)(A + r * EDIM + c8 * 8);
            const float4 a1 = *(const float4*)(A + r * EDIM + c8 * 8 + 4);
            const float4 b0 = *(const float4*)(B + r * EDIM + c8 * 8);
            const float4 b1 = *(const float4*)(B + r * EDIM + c8 * 8 + 4);
            f16x8 ha, hb;
            ha[0]=(_Float16)a0.x; ha[1]=(_Float16)a0.y; ha[2]=(_Float16)a0.z; ha[3]=(_Float16)a0.w;
            ha[4]=(_Float16)a1.x; ha[5]=(_Float16)a1.y; ha[6]=(_Float16)a1.z; ha[7]=(_Float16)a1.w;
            hb[0]=(_Float16)b0.x; hb[1]=(_Float16)b0.y; hb[2]=(_Float16)b0.z; hb[3]=(_Float16)b0.w;
            hb[4]=(_Float16)b1.x; hb[5]=(_Float16)b1.y; hb[6]=(_Float16)b1.z; hb[7]=(_Float16)b1.w;
            *(f16x8*)(As + r * LSTR + c8 * 8) = ha;
            *(f16x8*)(Bs + r * LSTR + c8 * 8) = hb;
        }
    }
    __syncthreads();

    const int lane = tid & 63;
    const int wid  = __builtin_amdgcn_readfirstlane(tid >> 6);
    const int l15  = lane & 15;
    const int quad = lane >> 4;

    f32x4 acc[2][8];
#pragma unroll
    for (int r = 0; r < 2; ++r)
#pragma unroll
        for (int c = 0; c < 8; ++c) acc[r][c] = (f32x4){0.f, 0.f, 0.f, 0.f};

#pragma unroll
    for (int ks = 0; ks < 4; ++ks) {
        f16x8 cfrag[8], rfrag[2];
#pragma unroll
        for (int c = 0; c < 8; ++c)
            cfrag[c] = *(const f16x8*)(Bs + (c * 16 + l15) * LSTR + ks * 32 + quad * 8);
#pragma unroll
        for (int r = 0; r < 2; ++r)
            rfrag[r] = *(const f16x8*)(As + (wid * 32 + r * 16 + l15) * LSTR + ks * 32 + quad * 8);
#pragma unroll
        for (int r = 0; r < 2; ++r)
#pragma unroll
            for (int c = 0; c < 8; ++c)
                acc[r][c] = __builtin_amdgcn_mfma_f32_16x16x32_f16(cfrag[c], rfrag[r], acc[r][c], 0, 0, 0);
    }

#pragma unroll
    for (int r = 0; r < 2; ++r) {
        const size_t row = rowbase + wid * 32 + r * 16 + l15;
#pragma unroll
        for (int c = 0; c < 8; ++c) {
            const int col = colbase + c * 16 + quad * 4;
            const float4 bv = *(const float4*)(bias + col);
            const f32x4 a = acc[r][c];
            f16x4 h;
            h[0] = (_Float16)(a[0] + bv.x); h[1] = (_Float16)(a[1] + bv.y);
            h[2] = (_Float16)(a[2] + bv.z); h[3] = (_Float16)(a[3] + bv.w);
            *(f16x4*)(Cout + row * 384 + col) = h;
        }
    }
}

// ---------------- fused flash attention + out-projection ----------------
// One block per sample (round-5 proven flash body). After flash, ctx rows are
// written to LDS (reusing the dead kvs buffer) and the out-projection runs as
// per-sample MFMA with wout fragments loaded from global (L2-hot fp16).
__global__ __launch_bounds__(256, 4) void attn_out_kernel(
    const _Float16* __restrict__ qkv,   // [TOTAL][384] fp16
    const int*      __restrict__ ag,
    const int*      __restrict__ offs,
    const _Float16* __restrict__ woh,   // [128][128] fp16
    const float*    __restrict__ bout,  // [128] f32
    float*          __restrict__ out)   // [TOTAL][128] f32
{
    __shared__ __align__(16) char smem[40960];   // kvs (flash) then ctx (out-proj)
    float*    kvsf = (float*)smem;               // 8 bufs x 1280 floats
    _Float16* ctxs = (_Float16*)smem;            // 64 x LSTR halfs (17.4 KB)

    const int b    = blockIdx.x;
    const int n    = ag[b];
    const int off  = offs[b];
    const int tid  = threadIdx.x;
    const int lane = tid & 63;
    const int wid  = __builtin_amdgcn_readfirstlane(tid >> 6);
    float* kw = kvsf + (wid * 2 + 0) * (AMAX * KVSTR);
    float* vw = kvsf + (wid * 2 + 1) * (AMAX * KVSTR);
    const bool valid = lane < n;
    const _Float16* rowp = qkv + (size_t)(off + lane) * 384;

    f16x8 oh0[2], oh1[2];   // ctx results for this wave's 2 heads

#pragma unroll
    for (int m = 0; m < 2; ++m) {
        const int h = wid * 2 + m;
        float qa[DHEAD], ka[DHEAD], va[DHEAD];
        if (valid) {
            const f16x8 q0 = *(const f16x8*)(rowp + h * 16);
            const f16x8 q1 = *(const f16x8*)(rowp + h * 16 + 8);
            const f16x8 k0 = *(const f16x8*)(rowp + 128 + h * 16);
            const f16x8 k1 = *(const f16x8*)(rowp + 128 + h * 16 + 8);
            const f16x8 v0 = *(const f16x8*)(rowp + 256 + h * 16);
            const f16x8 v1 = *(const f16x8*)(rowp + 256 + h * 16 + 8);
#pragma unroll
            for (int d = 0; d < 8; ++d) {
                qa[d] = (float)q0[d]; qa[d + 8] = (float)q1[d];
                ka[d] = (float)k0[d]; ka[d + 8] = (float)k1[d];
                va[d] = (float)v0[d]; va[d + 8] = (float)v1[d];
            }
        } else {
#pragma unroll
            for (int d = 0; d < DHEAD; ++d) { qa[d] = 0.f; ka[d] = 0.f; va[d] = 0.f; }
        }
#pragma unroll
        for (int d = 0; d < DHEAD; ++d) qa[d] *= 0.25f;   // 1/sqrt(16)
        // wave-private LDS stash, no barrier needed
#pragma unroll
        for (int d4 = 0; d4 < 4; ++d4) {
            *(float4*)(kw + lane * KVSTR + d4 * 4) = make_float4(ka[d4*4], ka[d4*4+1], ka[d4*4+2], ka[d4*4+3]);
            *(float4*)(vw + lane * KVSTR + d4 * 4) = make_float4(va[d4*4], va[d4*4+1], va[d4*4+2], va[d4*4+3]);
        }

        float mrun = -1e30f, lrun = 0.f;
        float cacc[DHEAD];
#pragma unroll
        for (int d = 0; d < DHEAD; ++d) cacc[d] = 0.f;
        const int nch = (n + 15) >> 4;
        for (int ch = 0; ch < nch; ++ch) {
            const int jb = ch << 4;
            float s[16], p[16];
#pragma unroll
            for (int jj = 0; jj < 16; ++jj) {
                const float4* kr = (const float4*)(kw + (jb + jj) * KVSTR);
                const float4 k0 = kr[0], k1 = kr[1], k2 = kr[2], k3 = kr[3];
                const float kk[16] = {k0.x,k0.y,k0.z,k0.w, k1.x,k1.y,k1.z,k1.w,
                                      k2.x,k2.y,k2.z,k2.w, k3.x,k3.y,k3.z,k3.w};
                float a = 0.f;
#pragma unroll
                for (int d = 0; d < DHEAD; ++d) a = fmaf(qa[d], kk[d], a);
                s[jj] = (jb + jj < n) ? a : -1e30f;
            }
            float mc = s[0];
#pragma unroll
            for (int jj = 1; jj < 16; ++jj) mc = fmaxf(mc, s[jj]);
            const float mnew  = fmaxf(mrun, mc);
            const float alpha = __expf(mrun - mnew);
            float psum = 0.f;
#pragma unroll
            for (int jj = 0; jj < 16; ++jj) { p[jj] = __expf(s[jj] - mnew); psum += p[jj]; }
            lrun = fmaf(lrun, alpha, psum);
#pragma unroll
            for (int d = 0; d < DHEAD; ++d) cacc[d] *= alpha;
#pragma unroll
            for (int jj = 0; jj < 16; ++jj) {
                const float4* vr = (const float4*)(vw + (jb + jj) * KVSTR);
                const float4 v0 = vr[0], v1 = vr[1], v2 = vr[2], v3 = vr[3];
                const float vv[16] = {v0.x,v0.y,v0.z,v0.w, v1.x,v1.y,v1.z,v1.w,
                                      v2.x,v2.y,v2.z,v2.w, v3.x,v3.y,v3.z,v3.w};
                const float pj = p[jj];
#pragma unroll
                for (int d = 0; d < DHEAD; ++d) cacc[d] = fmaf(pj, vv[d], cacc[d]);
            }
            mrun = mnew;
        }
        f16x8 o0, o1;
        if (valid) {
            const float inv = 1.0f / lrun;
#pragma unroll
            for (int d = 0; d < 8; ++d) {
                o0[d] = (_Float16)(cacc[d] * inv);
                o1[d] = (_Float16)(cacc[d + 8] * inv);
            }
        } else {
#pragma unroll
            for (int d = 0; d < 8; ++d) { o0[d] = (_Float16)0; o1[d] = (_Float16)0; }
        }
        oh0[m] = o0; oh1[m] = o1;
    }

    // ---- ctx -> LDS (reuse kvs space; zero rows for invalid lanes already in oh) ----
    __syncthreads();   // all waves done reading kvs
#pragma unroll
    for (int m = 0; m < 2; ++m) {
        const int h = wid * 2 + m;
        *(f16x8*)(ctxs + lane * LSTR + h * 16)     = oh0[m];
        *(f16x8*)(ctxs + lane * LSTR + h * 16 + 8) = oh1[m];
    }
    __syncthreads();

    // ---- out-projection: wave w handles row-tile w (16 rows); cols = all 128 ----
    const int l15  = lane & 15;
    const int quad = lane >> 4;
    const int nt   = (n + 15) >> 4;
    if (wid < nt) {
        f32x4 acc[8];
#pragma unroll
        for (int c = 0; c < 8; ++c) acc[c] = (f32x4){0.f, 0.f, 0.f, 0.f};
#pragma unroll
        for (int ks = 0; ks < 4; ++ks) {
            const f16x8 rfrag = *(const f16x8*)(ctxs + (wid * 16 + l15) * LSTR + ks * 32 + quad * 8);
            f16x8 cf[8];
#pragma unroll
            for (int c = 0; c < 8; ++c)
                cf[c] = *(const f16x8*)(woh + (c * 16 + l15) * EDIM + ks * 32 + quad * 8);
#pragma unroll
            for (int c = 0; c < 8; ++c)
                acc[c] = __builtin_amdgcn_mfma_f32_16x16x32_f16(cf[c], rfrag, acc[c], 0, 0, 0);
        }
        const int row = wid * 16 + l15;
        if (row < n) {
            float* orow = out + (size_t)(off + row) * EDIM;
#pragma unroll
            for (int c = 0; c < 8; ++c) {
                const int col = c * 16 + quad * 4;
                const float4 bv = *(const float4*)(bout + col);
                *(float4*)(orow + col) =
                    make_float4(acc[c][0] + bv.x, acc[c][1] + bv.y,
                                acc[c][2] + bv.z, acc[c][3] + bv.w);
            }
        }
    }
}

// ================= fallback: fused fp32 kernel (used if ws too small) =================
__global__ __launch_bounds__(256, 2) void attn_fused_kernel(
    const float* __restrict__ x, const float* __restrict__ win,
    const float* __restrict__ bin, const float* __restrict__ wout,
    const float* __restrict__ bout, const int* __restrict__ ag,
    const int* __restrict__ offs, float* __restrict__ out)
{
    __shared__ __align__(16) float xs[AMAX * XSTR];
    __shared__ __align__(16) float kvs[8][AMAX * KVSTR];
    const int b = blockIdx.x, n = ag[b], off = offs[b];
    const int tid = threadIdx.x, lane = tid & 63;
    const int wid = __builtin_amdgcn_readfirstlane(tid >> 6);
#pragma unroll
    for (int it = 0; it < 8; ++it) {
        const int f4 = it * 256 + tid;
        const int r = f4 >> 5, c = (f4 & 31) << 2;
        float4 v = make_float4(0.f, 0.f, 0.f, 0.f);
        if (r < n) v = *(const float4*)(x + (size_t)(off + r) * EDIM + c);
        float* d = xs + r * XSTR + c;
        d[0]=v.x; d[1]=v.y; d[2]=v.z; d[3]=v.w;
    }
    __syncthreads();
    float* kw = kvs[wid*2+0]; float* vw = kvs[wid*2+1];
    const float* xrow = xs + lane * XSTR;
    float ctxk[2][DHEAD];
#pragma unroll
    for (int m = 0; m < 2; ++m) {
        const int h = wid * 2 + m;
        float qa[DHEAD], ka[DHEAD], va[DHEAD];
#pragma unroll
        for (int d = 0; d < DHEAD; ++d) { qa[d]=0.f; ka[d]=0.f; va[d]=0.f; }
        const float* wq = win + (size_t)(h*DHEAD)*EDIM;
        const float* wk = win + (size_t)(EDIM + h*DHEAD)*EDIM;
        const float* wv = win + (size_t)(2*EDIM + h*DHEAD)*EDIM;
        for (int k = 0; k < EDIM; ++k) {
            const float xv = xrow[k];
#pragma unroll
            for (int d = 0; d < DHEAD; ++d) {
                qa[d] = fmaf(xv, wq[d*EDIM+k], qa[d]);
                ka[d] = fmaf(xv, wk[d*EDIM+k], ka[d]);
                va[d] = fmaf(xv, wv[d*EDIM+k], va[d]);
            }
        }
#pragma unroll
        for (int d = 0; d < DHEAD; ++d) {
            qa[d] = (qa[d] + bin[h*DHEAD+d]) * 0.25f;
            ka[d] += bin[EDIM + h*DHEAD + d];
            va[d] += bin[2*EDIM + h*DHEAD + d];
        }
#pragma unroll
        for (int d = 0; d < DHEAD; ++d) { kw[lane*KVSTR+d] = ka[d]; vw[lane*KVSTR+d] = va[d]; }
        float mrun = -1e30f, lrun = 0.f, cacc[DHEAD];
#pragma unroll
        for (int d = 0; d < DHEAD; ++d) cacc[d] = 0.f;
        const int nch = (n + 15) >> 4;
        for (int ch = 0; ch < nch; ++ch) {
            const int jb = ch << 4;
            float s[16], p[16];
#pragma unroll
            for (int jj = 0; jj < 16; ++jj) {
                const float4* kr = (const float4*)(kw + (jb + jj) * KVSTR);
                const float4 k0=kr[0],k1=kr[1],k2=kr[2],k3=kr[3];
                const float kk[16] = {k0.x,k0.y,k0.z,k0.w,k1.x,k1.y,k1.z,k1.w,
                                      k2.x,k2.y,k2.z,k2.w,k3.x,k3.y,k3.z,k3.w};
                float a = 0.f;
#pragma unroll
                for (int d = 0; d < DHEAD; ++d) a = fmaf(qa[d], kk[d], a);
                s[jj] = (jb + jj < n) ? a : -1e30f;
            }
            float mc = s[0];
#pragma unroll
            for (int jj = 1; jj < 16; ++jj) mc = fmaxf(mc, s[jj]);
            const float mnew = fmaxf(mrun, mc);
            const float alpha = __expf(mrun - mnew);
            float psum = 0.f;
#pragma unroll
            for (int jj = 0; jj < 16; ++jj) { p[jj] = __expf(s[jj]-mnew); psum += p[jj]; }
            lrun = fmaf(lrun, alpha, psum);
#pragma unroll
            for (int d = 0; d < DHEAD; ++d) cacc[d] *= alpha;
#pragma unroll
            for (int jj = 0; jj < 16; ++jj) {
                const float4* vr = (const float4*)(vw + (jb + jj) * KVSTR);
                const float4 v0=vr[0],v1=vr[1],v2=vr[2],v3=vr[3];
                const float vv[16] = {v0.x,v0.y,v0.z,v0.w,v1.x,v1.y,v1.z,v1.w,
                                      v2.x,v2.y,v2.z,v2.w,v3.x,v3.y,v3.z,v3.w};
                const float pj = p[jj];
#pragma unroll
                for (int d = 0; d < DHEAD; ++d) cacc[d] = fmaf(pj, vv[d], cacc[d]);
            }
            mrun = mnew;
        }
        const float inv = 1.0f / lrun;
#pragma unroll
        for (int d = 0; d < DHEAD; ++d) ctxk[m][d] = cacc[d] * inv;
    }
    __syncthreads();
#pragma unroll
    for (int m = 0; m < 2; ++m) {
        const int h = wid * 2 + m;
#pragma unroll
        for (int d = 0; d < DHEAD; ++d) xs[lane*XSTR + h*DHEAD + d] = ctxk[m][d];
    }
    __syncthreads();
    const int c0 = wid * 32;
#pragma unroll
    for (int ct = 0; ct < 4; ++ct) {
        const int cc = c0 + ct * 8;
        float a8[8];
#pragma unroll
        for (int j = 0; j < 8; ++j) a8[j] = 0.f;
#pragma unroll 4
        for (int e = 0; e < EDIM; ++e) {
            const float cv = xrow[e];
#pragma unroll
            for (int j = 0; j < 8; ++j) a8[j] = fmaf(cv, wout[(size_t)(cc+j)*EDIM+e], a8[j]);
        }
        if (lane < n) {
            float* orow = out + (size_t)(off + lane) * EDIM + cc;
#pragma unroll
            for (int j = 0; j < 8; ++j) orow[j] = a8[j] + bout[cc+j];
        }
    }
}

extern "C" void kernel_launch(void* const* d_in, const int* in_sizes, int n_in,
                              void* d_out, int out_size, void* d_ws, size_t ws_size,
                              hipStream_t stream) {
    const float* x   = (const float*)d_in[0];
    const float* win = (const float*)d_in[1];
    const float* bin = (const float*)d_in[2];
    const float* wo  = (const float*)d_in[3];
    const float* bo  = (const float*)d_in[4];
    const int*   ag  = (const int*)d_in[5];
    float* out = (float*)d_out;

    // ws layout: qkvh [TOTAL*384] f16 | woh [128*128] f16 | offs [NB] int
    const size_t need = ((size_t)TOTAL * 384 + 16384) * sizeof(_Float16) + NB * sizeof(int);
    if (ws_size >= need) {
        _Float16* qkvh = (_Float16*)d_ws;
        _Float16* woh  = qkvh + (size_t)TOTAL * 384;
        int* offs = (int*)(woh + 16384);
        scan_kernel<<<1, 256, 0, stream>>>(ag, offs, wo, woh);
        gemm_qkv_kernel<<<dim3(3, TOTAL / 128), 256, 0, stream>>>(x, win, bin, qkvh);
        attn_out_kernel<<<NB, 256, 0, stream>>>(qkvh, ag, offs, woh, bo, out);
    } else {
        int* offs = (int*)d_ws;
        scan_kernel<<<1, 256, 0, stream>>>(ag, offs, nullptr, nullptr);
        attn_fused_kernel<<<NB, 256, 0, stream>>>(x, win, bin, wo, bo, ag, offs, out);
    }
}